// Round 6
// baseline (59.937 us; speedup 1.0000x reference)
//
#include <hip/hip_runtime.h>
#include <hip/hip_bf16.h>
#include <math.h>

// Sizes: B=512, IN=512, D=64, L=256, WF=0.5
//
// Reduction (verified): output only uses mem_new[:L] = w[0, 0:256, :], so the
// write path collapses to a (256,256) coefficient matrix c[i,l], and
//   out[b] = sigmoid( sum_{i,l} c[i,l] * softmax_l(lf[b,:]@kernel_r[i,:,:])[l] )
// Two kernels: k_front (l1 + heads + accumulator init, one block per batch
// row), k_mainc (c + MFMA einsum + softmax + atomic reduce over i + last-block
// sigmoid finalize).

typedef __attribute__((ext_vector_type(8))) short short8;
typedef __attribute__((ext_vector_type(4))) float f32x4;

static __device__ __forceinline__ unsigned short f2bf(float f) {
    __hip_bfloat16 h = __float2bfloat16(f);
    return *reinterpret_cast<unsigned short*>(&h);
}

// Fused front-end, one block per batch row b (grid 512, 256 threads).
__global__ __launch_bounds__(256) void k_front(
    const float* __restrict__ x,
    const float* __restrict__ k1,  const float* __restrict__ b1,
    const float* __restrict__ k20, const float* __restrict__ b20,
    const float* __restrict__ k2,  const float* __restrict__ b2,
    const float* __restrict__ k30, const float* __restrict__ b30,
    const float* __restrict__ k3,  const float* __restrict__ b3,
    const float* __restrict__ k40, const float* __restrict__ b40,
    const float* __restrict__ k4,  const float* __restrict__ b4,
    unsigned short* __restrict__ lf_bf,  // (512,64) bf16
    float* __restrict__ lfw,             // (256,64)
    float* __restrict__ lbw0,            // (256)
    float* __restrict__ out_acc,         // (512) zeroed here each call
    unsigned int* __restrict__ done) {   // ticket counter, zeroed here
    __shared__ float xs[512];
    __shared__ float part[4][64];
    __shared__ float l1s[60];
    __shared__ float hid2[50], hid3[50], hid4[50];
    const int b = blockIdx.x, t = threadIdx.x;
    const int c = t & 63, kq = t >> 6;

    if (b == 511) {  // init accumulators for k_mainc (stream-ordered)
        out_acc[t] = 0.f;
        out_acc[t + 256] = 0.f;
        if (t == 0) *done = 0u;
    }

    xs[t] = x[b * 512 + t];
    xs[t + 256] = x[b * 512 + 256 + t];
    __syncthreads();

    // phase 1: 4-way K-split x 4 independent accumulators
    {
        float a0 = 0.f, a1 = 0.f, a2 = 0.f, a3 = 0.f;
        if (c < 60) {
            const float* xk = xs + kq * 128;
            const float* kp = k1 + (kq * 128) * 60 + c;
#pragma unroll 4
            for (int k = 0; k < 128; k += 4) {
                a0 += xk[k + 0] * kp[(k + 0) * 60];
                a1 += xk[k + 1] * kp[(k + 1) * 60];
                a2 += xk[k + 2] * kp[(k + 2) * 60];
                a3 += xk[k + 3] * kp[(k + 3) * 60];
            }
        }
        part[kq][c] = (a0 + a1) + (a2 + a3);
    }
    __syncthreads();
    if (t < 60)
        l1s[t] = fmaxf(b1[t] + part[0][t] + part[1][t] + part[2][t] + part[3][t], 0.f);
    __syncthreads();

    // phase 2: hidden layers (60 -> 50), one wave each
    if (t < 50) {
        float a = b20[t];
#pragma unroll
        for (int k = 0; k < 60; ++k) a += l1s[k] * k20[k * 50 + t];
        hid2[t] = fmaxf(a, 0.f);
    } else if (t >= 64 && t < 114 && b < 256) {
        const int j = t - 64;
        float a = b30[j];
#pragma unroll
        for (int k = 0; k < 60; ++k) a += l1s[k] * k30[k * 50 + j];
        hid3[j] = fmaxf(a, 0.f);
    } else if (t >= 128 && t < 178 && b == 0) {
        const int j = t - 128;
        float a = b40[j];
#pragma unroll
        for (int k = 0; k < 60; ++k) a += l1s[k] * k40[k * 50 + j];
        hid4[j] = fmaxf(a, 0.f);
    }
    __syncthreads();

    // phase 3: heads (50 -> 64), one wave each
    if (t < 64) {
        float a = b2[t];
#pragma unroll
        for (int k = 0; k < 50; ++k) a += hid2[k] * k2[k * 64 + t];
        lf_bf[b * 64 + t] = f2bf(fmaxf(a, 0.f));
    } else if (t < 128 && b < 256) {
        const int j = t - 64;
        float a = b3[j];
#pragma unroll
        for (int k = 0; k < 50; ++k) a += hid3[k] * k3[k * 64 + j];
        lfw[b * 64 + j] = fmaxf(a, 0.f);
    }
    if (b == 0) {
        __syncthreads();
        float a = b4[t];
#pragma unroll
        for (int k = 0; k < 50; ++k) a += hid4[k] * k4[k * 256 + t];
        lbw0[t] = tanhf(a);
    }
}

// Fused c-coefficients + MFMA einsum + softmax + atomic reduce + finalize.
// One block per i (grid 256), 512 threads = 8 waves. Each block covers ALL
// 512 batch rows for its i, so term(b,i) = sw/se completes in-block and is
// atomically accumulated into out_acc[b]. Last block (ticket 255) applies
// sigmoid and writes d_out.
__global__ __launch_bounds__(512, 2) void k_mainc(
    const unsigned short* __restrict__ lf,   // (512,64) bf16 bits
    const float* __restrict__ kernel_r,      // (256,64,256) f32
    const float* __restrict__ lfw,           // (256,64)
    const float* __restrict__ kw,            // (256,64,256), j=0 slice
    const float* __restrict__ mem,           // row 0 used
    const float* __restrict__ lbw0,          // (256)
    const float* __restrict__ wsig,          // (65536)
    float* __restrict__ out_acc,             // (512)
    unsigned int* __restrict__ done,
    float* __restrict__ out) {               // (512)
    __shared__ __align__(16) unsigned short KrT[256 * 64];  // 32 KB
    __shared__ float cLDS[256];
    __shared__ float wpart[4];
    __shared__ unsigned int lastflag;
    const int i = blockIdx.x;
    const int tid = threadIdx.x;
    const int lane = tid & 63;
    const int wv = tid >> 6;

    // Stage: transpose + f32->bf16, XOR-swizzled (byte ^= (l&7)<<4).
    {
        const int l = tid & 255;
        const int dh = tid >> 8;
        const int rot = ((l >> 3) & 15) * 2;
        const float* src = kernel_r + (size_t)i * 16384 + l;
        char* lds = (char*)KrT;
#pragma unroll
        for (int j = 0; j < 16; ++j) {
            const int d = dh * 32 + ((2 * j + rot) & 31);
            const float f0 = src[(size_t)d * 256];
            const float f1 = src[(size_t)(d + 1) * 256];
            const unsigned int pk =
                (unsigned int)f2bf(f0) | ((unsigned int)f2bf(f1) << 16);
            const int byteoff = ((l * 64 + d) * 2) ^ ((l & 7) << 4);
            *(unsigned int*)(lds + byteoff) = pk;
        }
    }

    // c-phase (threads 0..255, one l each). Logits O(0.04) -> no max-sub.
    float e_c = 0.f;
    if (tid < 256) {
        const int l = tid;
        float s = 0.f;
#pragma unroll 8
        for (int d = 0; d < 64; ++d) s += lfw[i * 64 + d] * kw[d * 256 + l];
        e_c = __expf(s);
        float se = e_c;
#pragma unroll
        for (int off = 1; off < 64; off <<= 1) se += __shfl_xor(se, off, 64);
        if (lane == 0) wpart[wv] = se;
    }
    __syncthreads();
    if (tid < 256) {
        const int l = tid;
        const float tot = wpart[0] + wpart[1] + wpart[2] + wpart[3];
        cLDS[l] = mem[l] * (e_c / tot) * (1.f + 0.5f * lbw0[l]) * wsig[i * 256 + l];
    }
    __syncthreads();

    const int c = lane & 15, g = lane >> 4;

    // B fragments: 16 N-tiles x 2 K-halves. B[k][col]: col = lane&15,
    // k = kh*32 + (lane>>4)*8 + j.
    short8 Bf0[16], Bf1[16];
    {
        const char* lds = (const char*)KrT;
#pragma unroll
        for (int n = 0; n < 16; ++n) {
            const int l = n * 16 + c;
            const int base = l * 128 + g * 16;
            Bf0[n] = *(const short8*)(lds + ((base) ^ ((l & 7) << 4)));
            Bf1[n] = *(const short8*)(lds + ((base + 64) ^ ((l & 7) << 4)));
        }
    }
    float ccv[16];
#pragma unroll
    for (int n = 0; n < 16; ++n) ccv[n] = cLDS[n * 16 + c];

#pragma unroll
    for (int p = 0; p < 4; ++p) {
        const int b0 = wv * 64 + p * 16;
        const short8 a0 = *(const short8*)(lf + (b0 + c) * 64 + g * 8);
        const short8 a1 = *(const short8*)(lf + (b0 + c) * 64 + 32 + g * 8);
        f32x4 acc[16];
#pragma unroll
        for (int n = 0; n < 16; ++n) acc[n] = (f32x4){0.f, 0.f, 0.f, 0.f};
#pragma unroll
        for (int n = 0; n < 16; ++n) {
            acc[n] = __builtin_amdgcn_mfma_f32_16x16x32_bf16(a0, Bf0[n], acc[n], 0, 0, 0);
            acc[n] = __builtin_amdgcn_mfma_f32_16x16x32_bf16(a1, Bf1[n], acc[n], 0, 0, 0);
        }
        // D layout: row = (lane>>4)*4 + r, col = n*16 + (lane&15).
#pragma unroll
        for (int r = 0; r < 4; ++r) {
            float se = 0.f, sw = 0.f;
#pragma unroll
            for (int n = 0; n < 16; ++n) {
                const float e = __expf(acc[n][r]);
                se += e;
                sw += ccv[n] * e;
            }
#pragma unroll
            for (int off = 1; off < 16; off <<= 1) {
                se += __shfl_xor(se, off, 64);
                sw += __shfl_xor(sw, off, 64);
            }
            if (c == 0) atomicAdd(&out_acc[b0 + g * 4 + r], sw / se);
        }
    }

    // Finalize: ticket; last block applies sigmoid.
    __syncthreads();
    if (tid == 0) {
        __threadfence();
        lastflag = __hip_atomic_fetch_add(done, 1u, __ATOMIC_ACQ_REL,
                                          __HIP_MEMORY_SCOPE_AGENT);
    }
    __syncthreads();
    if (lastflag == 255u) {
        const float v = __hip_atomic_load(&out_acc[tid], __ATOMIC_ACQUIRE,
                                          __HIP_MEMORY_SCOPE_AGENT);
        out[tid] = 1.f / (1.f + __expf(-v));
    }
}

extern "C" void kernel_launch(void* const* d_in, const int* in_sizes, int n_in,
                              void* d_out, int out_size, void* d_ws, size_t ws_size,
                              hipStream_t stream) {
    (void)in_sizes; (void)n_in; (void)out_size; (void)ws_size;
    const float* x    = (const float*)d_in[0];
    const float* mem  = (const float*)d_in[1];
    const float* k1   = (const float*)d_in[2];
    const float* b1   = (const float*)d_in[3];
    const float* k20  = (const float*)d_in[4];
    const float* b20  = (const float*)d_in[5];
    const float* k30  = (const float*)d_in[6];
    const float* b30  = (const float*)d_in[7];
    const float* k40  = (const float*)d_in[8];
    const float* b40  = (const float*)d_in[9];
    const float* k2   = (const float*)d_in[10];
    const float* b2   = (const float*)d_in[11];
    const float* k3   = (const float*)d_in[12];
    const float* b3   = (const float*)d_in[13];
    const float* k4   = (const float*)d_in[14];
    const float* b4   = (const float*)d_in[15];
    const float* kr   = (const float*)d_in[16];
    const float* kw   = (const float*)d_in[17];
    const float* wsig = (const float*)d_in[18];
    float* out = (float*)d_out;

    float* ws   = (float*)d_ws;
    float* lfw  = ws;                    // 256*64 f
    float* lbw0 = lfw + 256 * 64;        // 256 f
    float* oacc = lbw0 + 256;            // 512 f
    unsigned int* done = (unsigned int*)(oacc + 512);  // 1 u32 (+pad)
    unsigned short* lf_bf = (unsigned short*)(done + 64);  // 512*64 bf16

    hipLaunchKernelGGL(k_front, dim3(512), dim3(256), 0, stream, x,
                       k1, b1, k20, b20, k2, b2, k30, b30, k3, b3,
                       k40, b40, k4, b4, lf_bf, lfw, lbw0, oacc, done);
    hipLaunchKernelGGL(k_mainc, dim3(256), dim3(512), 0, stream,
                       lf_bf, kr, lfw, kw, mem, lbw0, wsig, oacc, done, out);
}

// Round 7
// 33.068 us; speedup vs baseline: 1.8126x; 1.8126x over previous
//
#include <hip/hip_runtime.h>
#include <hip/hip_bf16.h>
#include <math.h>

// Sizes: B=512, IN=512, D=64, L=256, WF=0.5
//
// Reduction (verified): output only uses mem_new[:L] = w[0, 0:256, :], so the
// write path collapses to a (256,256) coefficient matrix c[i,l], and
//   out[b] = sigmoid( sum_{i,l} c[i,l] * softmax_l(lf[b,:]@kernel_r[i,:,:])[l] )
//
// k_front: (a) blocks 0..511: l1 + heads (one block per batch row);
//          (b) blocks 512..767: convert kernel_r[i] -> KrT_all[i] bf16,
//              transposed to [l][d], row stride 144 B (pad => conflict-free
//              ds_read_b128 without XOR swizzle, and global_load_lds-linear).
// k_mainc: stage KrT_all[i] via global_load_lds (async DMA, overlapped with
//          the c-phase VALU work), MFMA einsum, fused softmax, partial store.
// k_out2:  reduce over i + sigmoid.

typedef __attribute__((ext_vector_type(8))) short short8;
typedef __attribute__((ext_vector_type(4))) float f32x4;
typedef __attribute__((ext_vector_type(4))) unsigned int u32x4;

#define KRT_STRIDE_B 144      // bytes per l-row (128 payload + 16 pad)
#define KRT_I_BYTES 40960     // per-i region: 256*144=36864, padded to 40 KB

static __device__ __forceinline__ unsigned short f2bf(float f) {
    __hip_bfloat16 h = __float2bfloat16(f);
    return *reinterpret_cast<unsigned short*>(&h);
}

// Fused front-end + kernel_r conversion.
__global__ __launch_bounds__(256) void k_front(
    const float* __restrict__ x,
    const float* __restrict__ k1,  const float* __restrict__ b1,
    const float* __restrict__ k20, const float* __restrict__ b20,
    const float* __restrict__ k2,  const float* __restrict__ b2,
    const float* __restrict__ k30, const float* __restrict__ b30,
    const float* __restrict__ k3,  const float* __restrict__ b3,
    const float* __restrict__ k40, const float* __restrict__ b40,
    const float* __restrict__ k4,  const float* __restrict__ b4,
    const float* __restrict__ kernel_r,   // (256,64,256) f32
    unsigned short* __restrict__ lf_bf,   // (512,64) bf16
    float* __restrict__ lfw,              // (256,64)
    float* __restrict__ lbw0,             // (256)
    unsigned short* __restrict__ krt) {   // KrT_all: 256 x 40960 B
    const int blk = blockIdx.x, t = threadIdx.x;

    if (blk >= 512) {
        // ---- conversion blocks: i = blk-512, thread t owns l = t ----
        const int i = blk - 512;
        const float* src = kernel_r + (size_t)i * 16384 + t;   // [d][l=t]
        unsigned short* dst = krt + (size_t)i * (KRT_I_BYTES / 2)
                                  + (size_t)t * (KRT_STRIDE_B / 2);
#pragma unroll
        for (int ch = 0; ch < 4; ++ch) {   // 16 d's per chunk -> 32 B write
            unsigned int pk[8];
#pragma unroll
            for (int j = 0; j < 8; ++j) {
                const float f0 = src[(size_t)(ch * 16 + 2 * j) * 256];
                const float f1 = src[(size_t)(ch * 16 + 2 * j + 1) * 256];
                pk[j] = (unsigned int)f2bf(f0) | ((unsigned int)f2bf(f1) << 16);
            }
            u32x4 w0 = (u32x4){pk[0], pk[1], pk[2], pk[3]};
            u32x4 w1 = (u32x4){pk[4], pk[5], pk[6], pk[7]};
            *(u32x4*)(dst + ch * 16) = w0;
            *(u32x4*)(dst + ch * 16 + 8) = w1;
        }
        return;
    }

    // ---- front blocks: one batch row b = blk ----
    __shared__ float xs[512];
    __shared__ float part[4][64];
    __shared__ float l1s[60];
    __shared__ float hid2[50], hid3[50], hid4[50];
    const int b = blk;
    const int c = t & 63, kq = t >> 6;

    xs[t] = x[b * 512 + t];
    xs[t + 256] = x[b * 512 + 256 + t];
    __syncthreads();

    // phase 1: 4-way K-split x 4 independent accumulators
    {
        float a0 = 0.f, a1 = 0.f, a2 = 0.f, a3 = 0.f;
        if (c < 60) {
            const float* xk = xs + kq * 128;
            const float* kp = k1 + (kq * 128) * 60 + c;
#pragma unroll 4
            for (int k = 0; k < 128; k += 4) {
                a0 += xk[k + 0] * kp[(k + 0) * 60];
                a1 += xk[k + 1] * kp[(k + 1) * 60];
                a2 += xk[k + 2] * kp[(k + 2) * 60];
                a3 += xk[k + 3] * kp[(k + 3) * 60];
            }
        }
        part[kq][c] = (a0 + a1) + (a2 + a3);
    }
    __syncthreads();
    if (t < 60)
        l1s[t] = fmaxf(b1[t] + part[0][t] + part[1][t] + part[2][t] + part[3][t], 0.f);
    __syncthreads();

    // phase 2: hidden layers (60 -> 50), one wave each
    if (t < 50) {
        float a = b20[t];
#pragma unroll
        for (int k = 0; k < 60; ++k) a += l1s[k] * k20[k * 50 + t];
        hid2[t] = fmaxf(a, 0.f);
    } else if (t >= 64 && t < 114 && b < 256) {
        const int j = t - 64;
        float a = b30[j];
#pragma unroll
        for (int k = 0; k < 60; ++k) a += l1s[k] * k30[k * 50 + j];
        hid3[j] = fmaxf(a, 0.f);
    } else if (t >= 128 && t < 178 && b == 0) {
        const int j = t - 128;
        float a = b40[j];
#pragma unroll
        for (int k = 0; k < 60; ++k) a += l1s[k] * k40[k * 50 + j];
        hid4[j] = fmaxf(a, 0.f);
    }
    __syncthreads();

    // phase 3: heads (50 -> 64), one wave each
    if (t < 64) {
        float a = b2[t];
#pragma unroll
        for (int k = 0; k < 50; ++k) a += hid2[k] * k2[k * 64 + t];
        lf_bf[b * 64 + t] = f2bf(fmaxf(a, 0.f));
    } else if (t < 128 && b < 256) {
        const int j = t - 64;
        float a = b3[j];
#pragma unroll
        for (int k = 0; k < 50; ++k) a += hid3[k] * k3[k * 64 + j];
        lfw[b * 64 + j] = fmaxf(a, 0.f);
    }
    if (b == 0) {
        __syncthreads();
        float a = b4[t];
#pragma unroll
        for (int k = 0; k < 50; ++k) a += hid4[k] * k4[k * 256 + t];
        lbw0[t] = tanhf(a);
    }
}

// Fused c-coefficients + MFMA einsum + softmax + partial store.
// One block per i (grid 256), 512 threads = 8 waves, 2 blocks/CU.
// Staging: 5 x global_load_lds dwordx4 per thread (async DMA), overlapped
// with the c-phase; LDS rows stride 144 B -> ds_read_b128 is 2-way (free).
__global__ __launch_bounds__(512, 2) void k_mainc(
    const unsigned short* __restrict__ lf,   // (512,64) bf16 bits
    const unsigned short* __restrict__ krt,  // KrT_all
    const float* __restrict__ lfw,           // (256,64)
    const float* __restrict__ kw,            // (256,64,256), j=0 slice
    const float* __restrict__ mem,           // row 0 used
    const float* __restrict__ lbw0,          // (256)
    const float* __restrict__ wsig,          // (65536)
    float* __restrict__ partial) {           // (512,256) [b][i]
    __shared__ __align__(16) unsigned char KrT[KRT_I_BYTES];  // 40 KB
    __shared__ float cLDS[256];
    __shared__ float wpart[4];
    const int i = blockIdx.x;
    const int tid = threadIdx.x;
    const int lane = tid & 63;
    const int wv = tid >> 6;

    // Issue async DMA stage first: 8 waves x 5 x 1 KB = 40 KB.
    {
        const char* gsrc = (const char*)krt + (size_t)i * KRT_I_BYTES
                           + (size_t)(wv * 5) * 1024 + (lane << 4);
        char* lds = (char*)KrT + (size_t)(wv * 5) * 1024;
#pragma unroll
        for (int k = 0; k < 5; ++k) {
            __builtin_amdgcn_global_load_lds(
                (const __attribute__((address_space(1))) void*)(gsrc + k * 1024),
                (__attribute__((address_space(3))) void*)(lds + k * 1024),
                16, 0, 0);
        }
    }

    // c-phase (threads 0..255, one l each) overlaps the DMA.
    // Logits O(0.04) -> no max-subtraction needed.
    float e_c = 0.f;
    if (tid < 256) {
        const int l = tid;
        float s = 0.f;
#pragma unroll 8
        for (int d = 0; d < 64; ++d) s += lfw[i * 64 + d] * kw[d * 256 + l];
        e_c = __expf(s);
        float se = e_c;
#pragma unroll
        for (int off = 1; off < 64; off <<= 1) se += __shfl_xor(se, off, 64);
        if (lane == 0) wpart[wv] = se;
    }
    __syncthreads();
    if (tid < 256) {
        const int l = tid;
        const float tot = wpart[0] + wpart[1] + wpart[2] + wpart[3];
        cLDS[l] = mem[l] * (e_c / tot) * (1.f + 0.5f * lbw0[l]) * wsig[i * 256 + l];
    }
    __syncthreads();

    const int c = lane & 15, g = lane >> 4;

    // B fragments: 16 N-tiles x 2 K-halves. B[k][col]: col = lane&15,
    // k = kh*32 + (lane>>4)*8 + j. Row l at byte l*144; d at byte 2d.
    short8 Bf0[16], Bf1[16];
    {
        const char* lds = (const char*)KrT;
#pragma unroll
        for (int n = 0; n < 16; ++n) {
            const int l = n * 16 + c;
            const char* row = lds + l * KRT_STRIDE_B + g * 16;
            Bf0[n] = *(const short8*)(row);
            Bf1[n] = *(const short8*)(row + 64);
        }
    }
    float ccv[16];
#pragma unroll
    for (int n = 0; n < 16; ++n) ccv[n] = cLDS[n * 16 + c];

#pragma unroll
    for (int p = 0; p < 4; ++p) {
        const int b0 = wv * 64 + p * 16;
        const short8 a0 = *(const short8*)(lf + (b0 + c) * 64 + g * 8);
        const short8 a1 = *(const short8*)(lf + (b0 + c) * 64 + 32 + g * 8);
        f32x4 acc[16];
#pragma unroll
        for (int n = 0; n < 16; ++n) acc[n] = (f32x4){0.f, 0.f, 0.f, 0.f};
#pragma unroll
        for (int n = 0; n < 16; ++n) {
            acc[n] = __builtin_amdgcn_mfma_f32_16x16x32_bf16(a0, Bf0[n], acc[n], 0, 0, 0);
            acc[n] = __builtin_amdgcn_mfma_f32_16x16x32_bf16(a1, Bf1[n], acc[n], 0, 0, 0);
        }
        // D layout: row = (lane>>4)*4 + r, col = n*16 + (lane&15).
        // Softmax over cols: in-lane over n, then 16-lane xor-reduce.
#pragma unroll
        for (int r = 0; r < 4; ++r) {
            float se = 0.f, sw = 0.f;
#pragma unroll
            for (int n = 0; n < 16; ++n) {
                const float e = __expf(acc[n][r]);
                se += e;
                sw += ccv[n] * e;
            }
#pragma unroll
            for (int off = 1; off < 16; off <<= 1) {
                se += __shfl_xor(se, off, 64);
                sw += __shfl_xor(sw, off, 64);
            }
            if (c == 0) partial[(b0 + g * 4 + r) * 256 + i] = sw / se;
        }
    }
}

// Final reduce: 8 rows per block, 64 lanes x f32x4 per row + shuffle reduce.
__global__ __launch_bounds__(256) void k_out2(const float* __restrict__ partial,
                                              float* __restrict__ out) {
    const int t = threadIdx.x;
    const int rq = t >> 6, lane = t & 63;
#pragma unroll
    for (int p = 0; p < 2; ++p) {
        const int row = blockIdx.x * 8 + p * 4 + rq;
        const f32x4 v = *(const f32x4*)&partial[row * 256 + lane * 4];
        float s = v.x + v.y + v.z + v.w;
#pragma unroll
        for (int off = 1; off < 64; off <<= 1) s += __shfl_xor(s, off, 64);
        if (lane == 0) out[row] = 1.f / (1.f + __expf(-s));
    }
}

extern "C" void kernel_launch(void* const* d_in, const int* in_sizes, int n_in,
                              void* d_out, int out_size, void* d_ws, size_t ws_size,
                              hipStream_t stream) {
    (void)in_sizes; (void)n_in; (void)out_size; (void)ws_size;
    const float* x    = (const float*)d_in[0];
    const float* mem  = (const float*)d_in[1];
    const float* k1   = (const float*)d_in[2];
    const float* b1   = (const float*)d_in[3];
    const float* k20  = (const float*)d_in[4];
    const float* b20  = (const float*)d_in[5];
    const float* k30  = (const float*)d_in[6];
    const float* b30  = (const float*)d_in[7];
    const float* k40  = (const float*)d_in[8];
    const float* b40  = (const float*)d_in[9];
    const float* k2   = (const float*)d_in[10];
    const float* b2   = (const float*)d_in[11];
    const float* k3   = (const float*)d_in[12];
    const float* b3   = (const float*)d_in[13];
    const float* k4   = (const float*)d_in[14];
    const float* b4   = (const float*)d_in[15];
    const float* kr   = (const float*)d_in[16];
    const float* kw   = (const float*)d_in[17];
    const float* wsig = (const float*)d_in[18];
    float* out = (float*)d_out;

    float* ws   = (float*)d_ws;
    float* lfw  = ws;                    // 256*64 f
    float* lbw0 = lfw + 256 * 64;        // 256 f
    float* part = lbw0 + 256;            // 512*256 f
    unsigned short* lf_bf = (unsigned short*)(part + 131072);      // 64 KB
    unsigned short* krt   = lf_bf + 512 * 64;                      // 10.5 MB

    hipLaunchKernelGGL(k_front, dim3(768), dim3(256), 0, stream, x,
                       k1, b1, k20, b20, k2, b2, k30, b30, k3, b3,
                       k40, b40, k4, b4, kr, lf_bf, lfw, lbw0, krt);
    hipLaunchKernelGGL(k_mainc, dim3(256), dim3(512), 0, stream,
                       lf_bf, krt, lfw, kw, mem, lbw0, wsig, part);
    hipLaunchKernelGGL(k_out2,  dim3(64),  dim3(256), 0, stream, part, out);
}